// Round 5
// baseline (177.588 us; speedup 1.0000x reference)
//
#include <hip/hip_runtime.h>
#include <hip/hip_bf16.h>

typedef __attribute__((ext_vector_type(4))) float f32x4;
typedef __attribute__((ext_vector_type(8))) short s16x8;
typedef __attribute__((ext_vector_type(4))) short s16x4;

#define DEVI __device__ __forceinline__

constexpr int S_LEN  = 2048;
constexpr int DMODEL = 1024;
constexpr int NH     = 16;
constexpr int HDIM   = 64;
constexpr int CHUNK  = 128;
constexpr int NCH    = S_LEN / CHUNK;   // 16

DEVI ushort f2bfu(float f){
  union { float f; uint u; } v; v.f = f;
  uint u = v.u;
  return (ushort)((u + 0x7fffu + ((u >> 16) & 1u)) >> 16);  // RNE
}
DEVI float bf2f(ushort u){ union { uint u; float f; } v; v.u = ((uint)u) << 16; return v.f; }

// -------------------------------------------------------------------------
// Kernel 1: fp32 -> bf16 conversion of x, weights; build combined qkv bias
// -------------------------------------------------------------------------
struct us4v { ushort a, b, c, d; };

DEVI void cvt_range(const float* __restrict__ src, ushort* __restrict__ dst,
                    long cnt4, long tid, long n){
  const f32x4* s = (const f32x4*)src;
  for (long i = tid; i < cnt4; i += n){
    f32x4 f = s[i];
    us4v o{ f2bfu(f[0]), f2bfu(f[1]), f2bfu(f[2]), f2bfu(f[3]) };
    *(us4v*)(dst + i*4) = o;
  }
}

__global__ __launch_bounds__(256)
void convert_kernel(const float* __restrict__ x,  const float* __restrict__ wqk,
                    const float* __restrict__ wqkb, const float* __restrict__ wv,
                    const float* __restrict__ wvb, const float* __restrict__ wo,
                    ushort* __restrict__ xbf, ushort* __restrict__ wqkv,
                    ushort* __restrict__ wobf, float* __restrict__ bqkv)
{
  long tid = (long)blockIdx.x*blockDim.x + threadIdx.x;
  long n   = (long)gridDim.x*blockDim.x;
  cvt_range(x,   xbf,            4194304/4, tid, n);
  cvt_range(wqk, wqkv,           2097152/4, tid, n);
  cvt_range(wv,  wqkv + 2097152, 1048576/4, tid, n);
  cvt_range(wo,  wobf,           1048576/4, tid, n);
  for (long i = tid; i < 2048; i += n) bqkv[i]        = wqkb[i];
  for (long i = tid; i < 1024; i += n) bqkv[2048 + i] = wvb[i];
}

// -------------------------------------------------------------------------
// Kernel 2: bf16 GEMM  C[M][N] = A[M][K] @ B[N][K]^T + bias  (128x128 tile)
//   1D grid + bijective XCD swizzle (bm-major); qkv epilogue (elu+1, scatter)
// -------------------------------------------------------------------------
__global__ __launch_bounds__(256)
void gemm_qkv(const ushort* __restrict__ A, const ushort* __restrict__ Bm,
              const float* __restrict__ bias, int K,
              ushort* __restrict__ qb, ushort* __restrict__ kb, ushort* __restrict__ vb)
{
  __shared__ __align__(16) ushort lds[2][2][128*32];
  const int tid = threadIdx.x;
  const int w = tid >> 6, l = tid & 63;
  const int l15 = l & 15, lg = l >> 4;
  const int wr = w >> 1, wc = w & 1;
  const int id = blockIdx.x;
  const int wg = (id & 7) * 96 + (id >> 3);
  const int bm = wg / 24, bn = wg % 24;
  const ushort* Ab = A  + (size_t)bm*128*K;
  const ushort* Bb = Bm + (size_t)bn*128*K;
  const int NT = K >> 5;

  f32x4 acc[4][4] = {};

  auto stage = [&](int buf, int kt){
    const ushort* gA = Ab + kt*32;
    const ushort* gB = Bb + kt*32;
    #pragma unroll
    for (int is = 0; is < 2; ++is){
      int f = is*256 + tid;
      int row = f >> 2, c8 = (f & 3) * 8;
      __builtin_amdgcn_global_load_lds(
        (const __attribute__((address_space(1))) void*)(gA + (size_t)row*K + c8),
        (__attribute__((address_space(3))) void*)&lds[buf][0][(is*256 + w*64)*8],
        16, 0, 0);
      __builtin_amdgcn_global_load_lds(
        (const __attribute__((address_space(1))) void*)(gB + (size_t)row*K + c8),
        (__attribute__((address_space(3))) void*)&lds[buf][1][(is*256 + w*64)*8],
        16, 0, 0);
    }
  };

  stage(0, 0);
  __syncthreads();
  int cur = 0;
  for (int kt = 0; kt < NT; ++kt){
    if (kt + 1 < NT) stage(cur ^ 1, kt + 1);
    s16x8 af[4], bfv[4];
    #pragma unroll
    for (int mi = 0; mi < 4; ++mi)
      af[mi] = *(const s16x8*)&lds[cur][0][(wr*64 + mi*16 + l15)*32 + lg*8];
    #pragma unroll
    for (int ni = 0; ni < 4; ++ni)
      bfv[ni] = *(const s16x8*)&lds[cur][1][(wc*64 + ni*16 + l15)*32 + lg*8];
    #pragma unroll
    for (int mi = 0; mi < 4; ++mi)
      #pragma unroll
      for (int ni = 0; ni < 4; ++ni)
        acc[mi][ni] = __builtin_amdgcn_mfma_f32_16x16x32_bf16(af[mi], bfv[ni], acc[mi][ni], 0, 0, 0);
    __syncthreads();
    cur ^= 1;
  }

  #pragma unroll
  for (int mi = 0; mi < 4; ++mi){
    #pragma unroll
    for (int ni = 0; ni < 4; ++ni){
      int col  = bn*128 + wc*64 + ni*16 + l15;
      float bv = bias[col];
      int row0 = bm*128 + wr*64 + mi*16 + lg*4;
      #pragma unroll
      for (int r = 0; r < 4; ++r){
        int tok = row0 + r;
        float val = acc[mi][ni][r] + bv;
        int bb = tok >> 11, ss = tok & 2047;
        if (col < 2048){
          val = val > 0.f ? val + 1.f : __expf(val);   // elu(x)+1
          int h = (col & 1023) >> 6, d = col & 63;
          ushort* dst = (col < 1024) ? qb : kb;
          dst[((size_t)(bb*NH + h)*S_LEN + ss)*HDIM + d] = f2bfu(val);
        } else {
          int cc = col - 2048; int h = cc >> 6, d = cc & 63;
          vb[((size_t)(bb*NH + h)*S_LEN + ss)*HDIM + d] = f2bfu(val);
        }
      }
    }
  }
}

// -------------------------------------------------------------------------
// Kernel 5: bf16 GEMM  out[M][N] = A[M][K] @ B[N][K]^T + bias  (fp32 out)
// -------------------------------------------------------------------------
__global__ __launch_bounds__(256)
void gemm_out(const ushort* __restrict__ A, const ushort* __restrict__ Bm,
              const float* __restrict__ bias, int K, int N,
              float* __restrict__ outp)
{
  __shared__ __align__(16) ushort ldsA[2][64*32];
  __shared__ __align__(16) ushort ldsB[2][128*32];
  const int tid = threadIdx.x;
  const int w = tid >> 6, l = tid & 63;
  const int l15 = l & 15, lg = l >> 4;
  const int wr = w >> 1, wc = w & 1;
  const int id = blockIdx.x;                 // nwg = 512
  const int wg = (id & 7) * 64 + (id >> 3);
  const int bm = wg >> 3, bn = wg & 7;
  const ushort* Ab = A  + (size_t)bm*64*K;
  const ushort* Bb = Bm + (size_t)bn*128*K;
  const int NT = K >> 5;

  f32x4 acc[2][4] = {};

  auto stage = [&](int buf, int kt){
    const ushort* gA = Ab + kt*32;
    const ushort* gB = Bb + kt*32;
    {
      int row = tid >> 2, c8 = (tid & 3) * 8;
      __builtin_amdgcn_global_load_lds(
        (const __attribute__((address_space(1))) void*)(gA + (size_t)row*K + c8),
        (__attribute__((address_space(3))) void*)&ldsA[buf][(w*64)*8],
        16, 0, 0);
    }
    #pragma unroll
    for (int is = 0; is < 2; ++is){
      int f = is*256 + tid;
      int row = f >> 2, c8 = (f & 3) * 8;
      __builtin_amdgcn_global_load_lds(
        (const __attribute__((address_space(1))) void*)(gB + (size_t)row*K + c8),
        (__attribute__((address_space(3))) void*)&ldsB[buf][(is*256 + w*64)*8],
        16, 0, 0);
    }
  };

  stage(0, 0);
  __syncthreads();
  int cur = 0;
  for (int kt = 0; kt < NT; ++kt){
    if (kt + 1 < NT) stage(cur ^ 1, kt + 1);
    s16x8 af[2], bfv[4];
    #pragma unroll
    for (int mi = 0; mi < 2; ++mi)
      af[mi] = *(const s16x8*)&ldsA[cur][(wr*32 + mi*16 + l15)*32 + lg*8];
    #pragma unroll
    for (int ni = 0; ni < 4; ++ni)
      bfv[ni] = *(const s16x8*)&ldsB[cur][(wc*64 + ni*16 + l15)*32 + lg*8];
    #pragma unroll
    for (int mi = 0; mi < 2; ++mi)
      #pragma unroll
      for (int ni = 0; ni < 4; ++ni)
        acc[mi][ni] = __builtin_amdgcn_mfma_f32_16x16x32_bf16(af[mi], bfv[ni], acc[mi][ni], 0, 0, 0);
    __syncthreads();
    cur ^= 1;
  }

  #pragma unroll
  for (int mi = 0; mi < 2; ++mi){
    #pragma unroll
    for (int ni = 0; ni < 4; ++ni){
      int col  = bn*128 + wc*64 + ni*16 + l15;
      float bv = bias[col];
      int row0 = bm*64 + wr*32 + mi*16 + lg*4;
      #pragma unroll
      for (int r = 0; r < 4; ++r)
        outp[(size_t)(row0 + r)*N + col] = acc[mi][ni][r] + bv;
    }
  }
}

// -------------------------------------------------------------------------
// Kernel 3: per-chunk partials   part[bh][c][t][d] = sum_s V[s][t]*K[s][d]
//           kpart[bh][c][d]      = sum_s K[s][d]
// -------------------------------------------------------------------------
__global__ __launch_bounds__(256)
void chunk_partial(const ushort* __restrict__ kb, const ushort* __restrict__ vb,
                   float* __restrict__ part, float* __restrict__ kpart)
{
  const int bh = blockIdx.x >> 4, c = blockIdx.x & 15;
  __shared__ __align__(16) float  Ksf[128*64];   // 32 KB fp32
  __shared__ __align__(16) ushort Vs[128*64];    // 16 KB bf16
  __shared__ float kred[4][64];
  const ushort* kg = kb + ((size_t)bh*S_LEN + c*CHUNK)*HDIM;
  const ushort* vg = vb + ((size_t)bh*S_LEN + c*CHUNK)*HDIM;
  const int tid = threadIdx.x;
  #pragma unroll
  for (int ii = 0; ii < 4; ++ii){
    int i = ii*256 + tid;               // 1024 groups of 8 elements
    s16x8 k8 = ((const s16x8*)kg)[i];
    ((s16x8*)Vs)[i] = ((const s16x8*)vg)[i];
    f32x4 lo, hi;
    #pragma unroll
    for (int j = 0; j < 4; ++j){ lo[j] = bf2f((ushort)k8[j]); hi[j] = bf2f((ushort)k8[4+j]); }
    *(f32x4*)&Ksf[i*8]     = lo;
    *(f32x4*)&Ksf[i*8 + 4] = hi;
  }
  __syncthreads();

  const int t0 = (tid >> 4) * 4;
  const int d0 = (tid & 15) * 4;
  f32x4 acc0 = {}, acc1 = {}, acc2 = {}, acc3 = {};
  for (int s = 0; s < 128; ++s){
    f32x4 kv = *(const f32x4*)&Ksf[s*64 + d0];
    s16x4 v4 = *(const s16x4*)&Vs[s*64 + t0];
    acc0 += bf2f((ushort)v4[0]) * kv;
    acc1 += bf2f((ushort)v4[1]) * kv;
    acc2 += bf2f((ushort)v4[2]) * kv;
    acc3 += bf2f((ushort)v4[3]) * kv;
  }
  float* dst = part + ((size_t)(bh*NCH + c))*4096 + (size_t)t0*64 + d0;
  *(f32x4*)&dst[0]   = acc0;
  *(f32x4*)&dst[64]  = acc1;
  *(f32x4*)&dst[128] = acc2;
  *(f32x4*)&dst[192] = acc3;

  // kpart: each quarter-block sums 32 rows of K for all 64 d
  {
    const int d = tid & 63, qq = tid >> 6;
    float s4 = 0.f;
    #pragma unroll 4
    for (int s = qq*32; s < qq*32 + 32; ++s) s4 += Ksf[s*64 + d];
    kred[qq][d] = s4;
  }
  __syncthreads();
  if (tid < 64)
    kpart[((size_t)(bh*NCH + c))*64 + tid] =
        kred[0][tid] + kred[1][tid] + kred[2][tid] + kred[3][tid];
}

// -------------------------------------------------------------------------
// Kernel 4: per-chunk attention with in-block exclusive prefix
//   S_excl = sum_{c<ch} part[bh][c]  (built bf16 in LDS)
//   kcum_excl = sum_{c<ch} kpart[bh][c]  (LDS)
//   A1 = Q K^T (causal, rowsum -> n) ; ctx = A1@V + Q@S_excl^T ; ctx *= 1/n
// -------------------------------------------------------------------------
__global__ __launch_bounds__(256)
void chunk_attn(const ushort* __restrict__ qb, const ushort* __restrict__ kb,
                const ushort* __restrict__ vb, const float* __restrict__ part,
                const float* __restrict__ kpart, ushort* __restrict__ ctx)
{
  const int bh = blockIdx.x >> 4, ch = blockIdx.x & 15;
  const int tid = threadIdx.x;
  const int w = tid >> 6, l = tid & 63;
  const int l15 = l & 15, lg = l >> 4;

  __shared__ __align__(16) ushort VT[64][136];     // V^T, padded
  __shared__ __align__(16) ushort Am[128][136];    // masked A, bf16, padded
  __shared__ __align__(16) ushort SxB[64][68];     // S_excl bf16 [t][d], padded
  __shared__ float kcx[64];
  __shared__ float nrow[128][2];
  __shared__ float ninv[128];

  const ushort* qg = qb + ((size_t)bh*S_LEN + ch*CHUNK)*HDIM;
  const ushort* kg = kb + ((size_t)bh*S_LEN + ch*CHUNK)*HDIM;
  const ushort* vg = vb + ((size_t)bh*S_LEN + ch*CHUNK)*HDIM;

  // exclusive prefix over chunk partials -> SxB (bf16), kcx
  if (ch > 0){
    const float* pb = part + (size_t)bh*NCH*4096;
    const int e0 = tid*16;                         // 16 elems per thread
    f32x4 s0 = {}, s1 = {}, s2 = {}, s3 = {};
    for (int c = 0; c < ch; ++c){
      const float* p = pb + (size_t)c*4096 + e0;
      s0 += *(const f32x4*)(p + 0);
      s1 += *(const f32x4*)(p + 4);
      s2 += *(const f32x4*)(p + 8);
      s3 += *(const f32x4*)(p + 12);
    }
    const int t = e0 >> 6, d = e0 & 63;
    s16x8 o0, o1;
    #pragma unroll
    for (int j = 0; j < 4; ++j){
      o0[j]   = (short)f2bfu(s0[j]); o0[4+j] = (short)f2bfu(s1[j]);
      o1[j]   = (short)f2bfu(s2[j]); o1[4+j] = (short)f2bfu(s3[j]);
    }
    *(s16x8*)&SxB[t][d]     = o0;
    *(s16x8*)&SxB[t][d + 8] = o1;
    if (tid < 64){
      const float* kpb = kpart + (size_t)bh*NCH*64;
      float kk = 0.f;
      for (int c = 0; c < ch; ++c) kk += kpb[c*64 + tid];
      kcx[tid] = kk;
    }
  }

  // transpose V into LDS
  {
    const int s = tid >> 1, t0 = (tid & 1) * 32;
    const ushort* src = vg + s*64 + t0;
    #pragma unroll
    for (int q8 = 0; q8 < 4; ++q8){
      s16x8 vv = *(const s16x8*)(src + q8*8);
      #pragma unroll
      for (int j = 0; j < 8; ++j) VT[t0 + q8*8 + j][s] = (ushort)vv[j];
    }
  }

  // stage 1: A1 = Q K^T, wave (wr,wc) owns 64x64; frags straight from global
  const int wr = w >> 1, wc = w & 1;
  f32x4 a1[4][4] = {};
  #pragma unroll
  for (int kst = 0; kst < 2; ++kst){
    s16x8 qa[4], kv[4];
    #pragma unroll
    for (int mi = 0; mi < 4; ++mi)
      qa[mi] = *(const s16x8*)(qg + (wr*64 + mi*16 + l15)*64 + kst*32 + lg*8);
    #pragma unroll
    for (int ni = 0; ni < 4; ++ni)
      kv[ni] = *(const s16x8*)(kg + (wc*64 + ni*16 + l15)*64 + kst*32 + lg*8);
    #pragma unroll
    for (int mi = 0; mi < 4; ++mi)
      #pragma unroll
      for (int ni = 0; ni < 4; ++ni)
        a1[mi][ni] = __builtin_amdgcn_mfma_f32_16x16x32_bf16(qa[mi], kv[ni], a1[mi][ni], 0,0,0);
  }

  // causal mask + rowsum + store bf16 A to LDS
  #pragma unroll
  for (int mi = 0; mi < 4; ++mi){
    float rs[4] = {0.f, 0.f, 0.f, 0.f};
    #pragma unroll
    for (int ni = 0; ni < 4; ++ni){
      int j = wc*64 + ni*16 + l15;
      #pragma unroll
      for (int r = 0; r < 4; ++r){
        int i = wr*64 + mi*16 + lg*4 + r;
        float v = (j <= i) ? a1[mi][ni][r] : 0.f;
        Am[i][j] = f2bfu(v);
        rs[r] += v;
      }
    }
    #pragma unroll
    for (int r = 0; r < 4; ++r){
      rs[r] += __shfl_xor(rs[r], 1);
      rs[r] += __shfl_xor(rs[r], 2);
      rs[r] += __shfl_xor(rs[r], 4);
      rs[r] += __shfl_xor(rs[r], 8);
    }
    if (l15 == 0){
      #pragma unroll
      for (int r = 0; r < 4; ++r)
        nrow[wr*64 + mi*16 + lg*4 + r][wc] = rs[r];
    }
  }
  __syncthreads();

  // n per row
  if (tid < 128){
    const ushort* qrow = qg + tid*64;
    float dot = 0.f;
    if (ch > 0){
      #pragma unroll
      for (int d = 0; d < 64; d += 8){
        s16x8 qv = *(const s16x8*)(qrow + d);
        #pragma unroll
        for (int e = 0; e < 8; ++e) dot += bf2f((ushort)qv[e]) * kcx[d + e];
      }
    }
    ninv[tid] = 1.f / (nrow[tid][0] + nrow[tid][1] + dot);
  }

  // stage 2: ctx = Am@V + Q@Sx^T ; wave owns rows w*32..+31, cols 0..63
  f32x4 a2[2][4] = {};
  #pragma unroll
  for (int kst = 0; kst < 4; ++kst){
    s16x8 pa[2], vv[4];
    #pragma unroll
    for (int mi = 0; mi < 2; ++mi)
      pa[mi] = *(const s16x8*)&Am[w*32 + mi*16 + l15][kst*32 + lg*8];
    #pragma unroll
    for (int ni = 0; ni < 4; ++ni)
      vv[ni] = *(const s16x8*)&VT[ni*16 + l15][kst*32 + lg*8];
    #pragma unroll
    for (int mi = 0; mi < 2; ++mi)
      #pragma unroll
      for (int ni = 0; ni < 4; ++ni)
        a2[mi][ni] = __builtin_amdgcn_mfma_f32_16x16x32_bf16(pa[mi], vv[ni], a2[mi][ni], 0,0,0);
  }
  if (ch > 0){
    #pragma unroll
    for (int kst = 0; kst < 2; ++kst){
      s16x8 qa2[2], sb[4];
      #pragma unroll
      for (int mi = 0; mi < 2; ++mi)
        qa2[mi] = *(const s16x8*)(qg + (w*32 + mi*16 + l15)*64 + kst*32 + lg*8);
      #pragma unroll
      for (int ni = 0; ni < 4; ++ni)
        sb[ni] = *(const s16x8*)&SxB[ni*16 + l15][kst*32 + lg*8];
      #pragma unroll
      for (int mi = 0; mi < 2; ++mi)
        #pragma unroll
        for (int ni = 0; ni < 4; ++ni)
          a2[mi][ni] = __builtin_amdgcn_mfma_f32_16x16x32_bf16(qa2[mi], sb[ni], a2[mi][ni], 0,0,0);
    }
  }
  __syncthreads();

  const int bbi = bh >> 4, h = bh & 15;
  #pragma unroll
  for (int mi = 0; mi < 2; ++mi){
    #pragma unroll
    for (int ni = 0; ni < 4; ++ni){
      int t  = ni*16 + l15;
      int i0 = w*32 + mi*16 + lg*4;
      #pragma unroll
      for (int r = 0; r < 4; ++r){
        int i = i0 + r;
        float v = a2[mi][ni][r] * ninv[i];
        int sg = ch*CHUNK + i;
        ctx[((size_t)bbi*S_LEN + sg)*DMODEL + h*HDIM + t] = f2bfu(v);
      }
    }
  }
}

// -------------------------------------------------------------------------
extern "C" void kernel_launch(void* const* d_in, const int* in_sizes, int n_in,
                              void* d_out, int out_size, void* d_ws, size_t ws_size,
                              hipStream_t stream)
{
  const float* x    = (const float*)d_in[0];
  const float* wqk  = (const float*)d_in[1];
  const float* wqkb = (const float*)d_in[2];
  const float* wv   = (const float*)d_in[3];
  const float* wvb  = (const float*)d_in[4];
  const float* wo   = (const float*)d_in[5];
  const float* wob  = (const float*)d_in[6];
  float* out = (float*)d_out;

  char* ws = (char*)d_ws;
  size_t o = 0;
  auto alloc = [&](size_t bytes){ size_t r = o; o += (bytes + 255) & ~(size_t)255; return r; };
  ushort* xbf  = (ushort*)(ws + alloc((size_t)4194304*2));   // reused as ctx later
  ushort* wqkv = (ushort*)(ws + alloc((size_t)3145728*2));
  ushort* wobf = (ushort*)(ws + alloc((size_t)1048576*2));
  float*  bqkv = (float*) (ws + alloc((size_t)3072*4));
  ushort* qbuf = (ushort*)(ws + alloc((size_t)4194304*2));
  ushort* kbuf = (ushort*)(ws + alloc((size_t)4194304*2));
  ushort* vbuf = (ushort*)(ws + alloc((size_t)4194304*2));
  float*  part = (float*) (ws + alloc((size_t)32*16*4096*4));
  float*  kprt = (float*) (ws + alloc((size_t)32*16*64*4));
  ushort* ctxb = xbf;   // x_bf no longer needed after QKV GEMM

  convert_kernel<<<2048, 256, 0, stream>>>(x, wqk, wqkb, wv, wvb, wo, xbf, wqkv, wobf, bqkv);
  gemm_qkv<<<768, 256, 0, stream>>>(xbf, wqkv, bqkv, 1024, qbuf, kbuf, vbuf);
  chunk_partial<<<512, 256, 0, stream>>>(kbuf, vbuf, part, kprt);
  chunk_attn<<<512, 256, 0, stream>>>(qbuf, kbuf, vbuf, part, kprt, ctxb);
  gemm_out<<<512, 256, 0, stream>>>(ctxb, wobf, wob, 1024, 1024, out);
}

// Round 6
// 175.351 us; speedup vs baseline: 1.0128x; 1.0128x over previous
//
#include <hip/hip_runtime.h>
#include <hip/hip_bf16.h>

typedef __attribute__((ext_vector_type(4))) float f32x4;
typedef __attribute__((ext_vector_type(8))) short s16x8;
typedef __attribute__((ext_vector_type(4))) short s16x4;

#define DEVI __device__ __forceinline__

constexpr int S_LEN  = 2048;
constexpr int DMODEL = 1024;
constexpr int NH     = 16;
constexpr int HDIM   = 64;
constexpr int CHUNK  = 128;
constexpr int NCH    = S_LEN / CHUNK;   // 16

DEVI ushort f2bfu(float f){
  union { float f; uint u; } v; v.f = f;
  uint u = v.u;
  return (ushort)((u + 0x7fffu + ((u >> 16) & 1u)) >> 16);  // RNE
}
DEVI float bf2f(ushort u){ union { uint u; float f; } v; v.u = ((uint)u) << 16; return v.f; }

// -------------------------------------------------------------------------
// Kernel 1: fp32 -> bf16 conversion of x, weights; build combined qkv bias
// -------------------------------------------------------------------------
struct us4v { ushort a, b, c, d; };

DEVI void cvt_range(const float* __restrict__ src, ushort* __restrict__ dst,
                    long cnt4, long tid, long n){
  const f32x4* s = (const f32x4*)src;
  for (long i = tid; i < cnt4; i += n){
    f32x4 f = s[i];
    us4v o{ f2bfu(f[0]), f2bfu(f[1]), f2bfu(f[2]), f2bfu(f[3]) };
    *(us4v*)(dst + i*4) = o;
  }
}

__global__ __launch_bounds__(256)
void convert_kernel(const float* __restrict__ x,  const float* __restrict__ wqk,
                    const float* __restrict__ wqkb, const float* __restrict__ wv,
                    const float* __restrict__ wvb, const float* __restrict__ wo,
                    ushort* __restrict__ xbf, ushort* __restrict__ wqkv,
                    ushort* __restrict__ wobf, float* __restrict__ bqkv)
{
  long tid = (long)blockIdx.x*blockDim.x + threadIdx.x;
  long n   = (long)gridDim.x*blockDim.x;
  cvt_range(x,   xbf,            4194304/4, tid, n);
  cvt_range(wqk, wqkv,           2097152/4, tid, n);
  cvt_range(wv,  wqkv + 2097152, 1048576/4, tid, n);
  cvt_range(wo,  wobf,           1048576/4, tid, n);
  for (long i = tid; i < 2048; i += n) bqkv[i]        = wqkb[i];
  for (long i = tid; i < 1024; i += n) bqkv[2048 + i] = wvb[i];
}

// -------------------------------------------------------------------------
// Kernel 2: bf16 GEMM  C[M][N] = A[M][K] @ B[N][K]^T + bias
//   BM=128, BN=96 -> grid 32x32 = 1024 blocks = 4 blocks/CU (barrier-drain
//   overlap per m103/m114).  qkv epilogue: elu+1 on q/k, scatter per element.
// -------------------------------------------------------------------------
__global__ __launch_bounds__(256)
void gemm_qkv(const ushort* __restrict__ A, const ushort* __restrict__ Bm,
              const float* __restrict__ bias, int K,
              ushort* __restrict__ qb, ushort* __restrict__ kb, ushort* __restrict__ vb)
{
  __shared__ __align__(16) ushort ldsA[2][128*32];
  __shared__ __align__(16) ushort ldsB[2][96*32];
  const int tid = threadIdx.x;
  const int w = tid >> 6, l = tid & 63;
  const int l15 = l & 15, lg = l >> 4;
  const int wr = w >> 1, wc = w & 1;
  // XCD swizzle: nwg = 1024 (divisible by 8); consecutive wg share bm
  const int id = blockIdx.x;
  const int wg = (id & 7) * 128 + (id >> 3);
  const int bm = wg >> 5, bn = wg & 31;
  const ushort* Ab = A  + (size_t)bm*128*K;
  const ushort* Bb = Bm + (size_t)bn*96*K;
  const int NT = K >> 5;

  f32x4 acc[4][3] = {};

  auto stage = [&](int buf, int kt){
    const ushort* gA = Ab + kt*32;
    const ushort* gB = Bb + kt*32;
    #pragma unroll
    for (int is = 0; is < 2; ++is){
      int f = is*256 + tid;
      {
        int row = f >> 2, c8 = (f & 3) * 8;
        __builtin_amdgcn_global_load_lds(
          (const __attribute__((address_space(1))) void*)(gA + (size_t)row*K + c8),
          (__attribute__((address_space(3))) void*)&ldsA[buf][f*8],
          16, 0, 0);
      }
      if (f < 384){   // B tile: 96 rows x 32 cols = 384 x 16B; wave-uniform mask
        int row = f >> 2, c8 = (f & 3) * 8;
        __builtin_amdgcn_global_load_lds(
          (const __attribute__((address_space(1))) void*)(gB + (size_t)row*K + c8),
          (__attribute__((address_space(3))) void*)&ldsB[buf][f*8],
          16, 0, 0);
      }
    }
  };

  stage(0, 0);
  __syncthreads();
  int cur = 0;
  for (int kt = 0; kt < NT; ++kt){
    if (kt + 1 < NT) stage(cur ^ 1, kt + 1);
    s16x8 af[4], bfv[3];
    #pragma unroll
    for (int mi = 0; mi < 4; ++mi)
      af[mi] = *(const s16x8*)&ldsA[cur][(wr*64 + mi*16 + l15)*32 + lg*8];
    #pragma unroll
    for (int ni = 0; ni < 3; ++ni)
      bfv[ni] = *(const s16x8*)&ldsB[cur][(wc*48 + ni*16 + l15)*32 + lg*8];
    #pragma unroll
    for (int mi = 0; mi < 4; ++mi)
      #pragma unroll
      for (int ni = 0; ni < 3; ++ni)
        acc[mi][ni] = __builtin_amdgcn_mfma_f32_16x16x32_bf16(af[mi], bfv[ni], acc[mi][ni], 0, 0, 0);
    __syncthreads();
    cur ^= 1;
  }

  #pragma unroll
  for (int mi = 0; mi < 4; ++mi){
    #pragma unroll
    for (int ni = 0; ni < 3; ++ni){
      int col  = bn*96 + wc*48 + ni*16 + l15;
      float bv = bias[col];
      int row0 = bm*128 + wr*64 + mi*16 + lg*4;
      #pragma unroll
      for (int r = 0; r < 4; ++r){
        int tok = row0 + r;
        float val = acc[mi][ni][r] + bv;
        int bb = tok >> 11, ss = tok & 2047;
        if (col < 2048){
          val = val > 0.f ? val + 1.f : __expf(val);   // elu(x)+1
          int h = (col & 1023) >> 6, d = col & 63;
          ushort* dst = (col < 1024) ? qb : kb;
          dst[((size_t)(bb*NH + h)*S_LEN + ss)*HDIM + d] = f2bfu(val);
        } else {
          int cc = col - 2048; int h = cc >> 6, d = cc & 63;
          vb[((size_t)(bb*NH + h)*S_LEN + ss)*HDIM + d] = f2bfu(val);
        }
      }
    }
  }
}

// -------------------------------------------------------------------------
// Kernel 6: bf16 GEMM  out[M][N] = A[M][K] @ B[N][K]^T + bias  (fp32 out)
//   BM=64, BN=128; 1D grid 512 + XCD swizzle
// -------------------------------------------------------------------------
__global__ __launch_bounds__(256)
void gemm_out(const ushort* __restrict__ A, const ushort* __restrict__ Bm,
              const float* __restrict__ bias, int K, int N,
              float* __restrict__ outp)
{
  __shared__ __align__(16) ushort ldsA[2][64*32];
  __shared__ __align__(16) ushort ldsB[2][128*32];
  const int tid = threadIdx.x;
  const int w = tid >> 6, l = tid & 63;
  const int l15 = l & 15, lg = l >> 4;
  const int wr = w >> 1, wc = w & 1;
  const int id = blockIdx.x;                 // nwg = 512
  const int wg = (id & 7) * 64 + (id >> 3);
  const int bm = wg >> 3, bn = wg & 7;
  const ushort* Ab = A  + (size_t)bm*64*K;
  const ushort* Bb = Bm + (size_t)bn*128*K;
  const int NT = K >> 5;

  f32x4 acc[2][4] = {};

  auto stage = [&](int buf, int kt){
    const ushort* gA = Ab + kt*32;
    const ushort* gB = Bb + kt*32;
    {
      int row = tid >> 2, c8 = (tid & 3) * 8;
      __builtin_amdgcn_global_load_lds(
        (const __attribute__((address_space(1))) void*)(gA + (size_t)row*K + c8),
        (__attribute__((address_space(3))) void*)&ldsA[buf][(w*64)*8],
        16, 0, 0);
    }
    #pragma unroll
    for (int is = 0; is < 2; ++is){
      int f = is*256 + tid;
      int row = f >> 2, c8 = (f & 3) * 8;
      __builtin_amdgcn_global_load_lds(
        (const __attribute__((address_space(1))) void*)(gB + (size_t)row*K + c8),
        (__attribute__((address_space(3))) void*)&ldsB[buf][(is*256 + w*64)*8],
        16, 0, 0);
    }
  };

  stage(0, 0);
  __syncthreads();
  int cur = 0;
  for (int kt = 0; kt < NT; ++kt){
    if (kt + 1 < NT) stage(cur ^ 1, kt + 1);
    s16x8 af[2], bfv[4];
    #pragma unroll
    for (int mi = 0; mi < 2; ++mi)
      af[mi] = *(const s16x8*)&ldsA[cur][(wr*32 + mi*16 + l15)*32 + lg*8];
    #pragma unroll
    for (int ni = 0; ni < 4; ++ni)
      bfv[ni] = *(const s16x8*)&ldsB[cur][(wc*64 + ni*16 + l15)*32 + lg*8];
    #pragma unroll
    for (int mi = 0; mi < 2; ++mi)
      #pragma unroll
      for (int ni = 0; ni < 4; ++ni)
        acc[mi][ni] = __builtin_amdgcn_mfma_f32_16x16x32_bf16(af[mi], bfv[ni], acc[mi][ni], 0, 0, 0);
    __syncthreads();
    cur ^= 1;
  }

  #pragma unroll
  for (int mi = 0; mi < 2; ++mi){
    #pragma unroll
    for (int ni = 0; ni < 4; ++ni){
      int col  = bn*128 + wc*64 + ni*16 + l15;
      float bv = bias[col];
      int row0 = bm*64 + wr*32 + mi*16 + lg*4;
      #pragma unroll
      for (int r = 0; r < 4; ++r)
        outp[(size_t)(row0 + r)*N + col] = acc[mi][ni][r] + bv;
    }
  }
}

// -------------------------------------------------------------------------
// Kernel 3: per-chunk partials   part[bh][c][t][d] = sum_s V[s][t]*K[s][d]
//           kpart[bh][c][d]      = sum_s K[s][d]
// -------------------------------------------------------------------------
__global__ __launch_bounds__(256)
void chunk_partial(const ushort* __restrict__ kb, const ushort* __restrict__ vb,
                   float* __restrict__ part, float* __restrict__ kpart)
{
  const int bh = blockIdx.x >> 4, c = blockIdx.x & 15;
  __shared__ __align__(16) float  Ksf[128*64];   // 32 KB fp32
  __shared__ __align__(16) ushort Vs[128*64];    // 16 KB bf16
  __shared__ float kred[4][64];
  const ushort* kg = kb + ((size_t)bh*S_LEN + c*CHUNK)*HDIM;
  const ushort* vg = vb + ((size_t)bh*S_LEN + c*CHUNK)*HDIM;
  const int tid = threadIdx.x;
  #pragma unroll
  for (int ii = 0; ii < 4; ++ii){
    int i = ii*256 + tid;               // 1024 groups of 8 elements
    s16x8 k8 = ((const s16x8*)kg)[i];
    ((s16x8*)Vs)[i] = ((const s16x8*)vg)[i];
    f32x4 lo, hi;
    #pragma unroll
    for (int j = 0; j < 4; ++j){ lo[j] = bf2f((ushort)k8[j]); hi[j] = bf2f((ushort)k8[4+j]); }
    *(f32x4*)&Ksf[i*8]     = lo;
    *(f32x4*)&Ksf[i*8 + 4] = hi;
  }
  __syncthreads();

  const int t0 = (tid >> 4) * 4;
  const int d0 = (tid & 15) * 4;
  f32x4 acc0 = {}, acc1 = {}, acc2 = {}, acc3 = {};
  for (int s = 0; s < 128; ++s){
    f32x4 kv = *(const f32x4*)&Ksf[s*64 + d0];
    s16x4 v4 = *(const s16x4*)&Vs[s*64 + t0];
    acc0 += bf2f((ushort)v4[0]) * kv;
    acc1 += bf2f((ushort)v4[1]) * kv;
    acc2 += bf2f((ushort)v4[2]) * kv;
    acc3 += bf2f((ushort)v4[3]) * kv;
  }
  float* dst = part + ((size_t)(bh*NCH + c))*4096 + (size_t)t0*64 + d0;
  *(f32x4*)&dst[0]   = acc0;
  *(f32x4*)&dst[64]  = acc1;
  *(f32x4*)&dst[128] = acc2;
  *(f32x4*)&dst[192] = acc3;

  // kpart: each quarter-block sums 32 rows of K for all 64 d
  {
    const int d = tid & 63, qq = tid >> 6;
    float s4 = 0.f;
    #pragma unroll 4
    for (int s = qq*32; s < qq*32 + 32; ++s) s4 += Ksf[s*64 + d];
    kred[qq][d] = s4;
  }
  __syncthreads();
  if (tid < 64)
    kpart[((size_t)(bh*NCH + c))*64 + tid] =
        kred[0][tid] + kred[1][tid] + kred[2][tid] + kred[3][tid];
}

// -------------------------------------------------------------------------
// Kernel 4: exclusive scan over chunks (per bh).  512 blocks; all 16 loads
// issued up-front (independent) -> prefix in regs -> stores.
// -------------------------------------------------------------------------
__global__ __launch_bounds__(256)
void scan_chunks(float* __restrict__ part, float* __restrict__ kpart)
{
  const int bh = blockIdx.x >> 4, seg = blockIdx.x & 15;
  const int tid = threadIdx.x;
  const size_t pb = (size_t)bh * NCH * 4096;
  const int e = seg*256 + tid;
  float v[16];
  #pragma unroll
  for (int c = 0; c < 16; ++c) v[c] = part[pb + (size_t)c*4096 + e];
  float r = 0.f;
  #pragma unroll
  for (int c = 0; c < 16; ++c){ part[pb + (size_t)c*4096 + e] = r; r += v[c]; }
  if (seg == 0 && tid < 64){
    const size_t kbase = (size_t)bh * NCH * 64;
    float kv[16];
    #pragma unroll
    for (int c = 0; c < 16; ++c) kv[c] = kpart[kbase + c*64 + tid];
    float kr = 0.f;
    #pragma unroll
    for (int c = 0; c < 16; ++c){ kpart[kbase + c*64 + tid] = kr; kr += kv[c]; }
  }
}

// -------------------------------------------------------------------------
// Kernel 5: per-chunk attention
//   A1 = Q K^T (causal mask, rowsum -> n) ; ctx = A1@V + Q@S_excl ; ctx *= 1/n
// -------------------------------------------------------------------------
__global__ __launch_bounds__(256)
void chunk_attn(const ushort* __restrict__ qb, const ushort* __restrict__ kb,
                const ushort* __restrict__ vb, const float* __restrict__ sexcl,
                const float* __restrict__ kexcl, ushort* __restrict__ ctx)
{
  const int bh = blockIdx.x >> 4, c = blockIdx.x & 15;
  const int tid = threadIdx.x;
  const int w = tid >> 6, l = tid & 63;
  const int l15 = l & 15, lg = l >> 4;

  __shared__ __align__(16) ushort VT[64][136];     // V^T, padded
  __shared__ __align__(16) ushort Am[128][136];    // masked A, bf16, padded
  __shared__ float nrow[128][2];
  __shared__ float ninv[128];

  const ushort* qg = qb + ((size_t)bh*S_LEN + c*CHUNK)*HDIM;
  const ushort* kg = kb + ((size_t)bh*S_LEN + c*CHUNK)*HDIM;
  const ushort* vg = vb + ((size_t)bh*S_LEN + c*CHUNK)*HDIM;

  // transpose V into LDS
  {
    const int s = tid >> 1, t0 = (tid & 1) * 32;
    const ushort* src = vg + s*64 + t0;
    #pragma unroll
    for (int q8 = 0; q8 < 4; ++q8){
      s16x8 vv = *(const s16x8*)(src + q8*8);
      #pragma unroll
      for (int j = 0; j < 8; ++j) VT[t0 + q8*8 + j][s] = (ushort)vv[j];
    }
  }

  // stage 1: A1 = Q K^T, wave (wr,wc) owns 64x64; frags straight from global
  const int wr = w >> 1, wc = w & 1;
  f32x4 a1[4][4] = {};
  #pragma unroll
  for (int kst = 0; kst < 2; ++kst){
    s16x8 qa[4], kv[4];
    #pragma unroll
    for (int mi = 0; mi < 4; ++mi)
      qa[mi] = *(const s16x8*)(qg + (wr*64 + mi*16 + l15)*64 + kst*32 + lg*8);
    #pragma unroll
    for (int ni = 0; ni < 4; ++ni)
      kv[ni] = *(const s16x8*)(kg + (wc*64 + ni*16 + l15)*64 + kst*32 + lg*8);
    #pragma unroll
    for (int mi = 0; mi < 4; ++mi)
      #pragma unroll
      for (int ni = 0; ni < 4; ++ni)
        a1[mi][ni] = __builtin_amdgcn_mfma_f32_16x16x32_bf16(qa[mi], kv[ni], a1[mi][ni], 0,0,0);
  }

  // causal mask + rowsum + store bf16 A to LDS
  #pragma unroll
  for (int mi = 0; mi < 4; ++mi){
    float rs[4] = {0.f, 0.f, 0.f, 0.f};
    #pragma unroll
    for (int ni = 0; ni < 4; ++ni){
      int j = wc*64 + ni*16 + l15;
      #pragma unroll
      for (int r = 0; r < 4; ++r){
        int i = wr*64 + mi*16 + lg*4 + r;
        float v = (j <= i) ? a1[mi][ni][r] : 0.f;
        Am[i][j] = f2bfu(v);
        rs[r] += v;
      }
    }
    #pragma unroll
    for (int r = 0; r < 4; ++r){
      rs[r] += __shfl_xor(rs[r], 1);
      rs[r] += __shfl_xor(rs[r], 2);
      rs[r] += __shfl_xor(rs[r], 4);
      rs[r] += __shfl_xor(rs[r], 8);
    }
    if (l15 == 0){
      #pragma unroll
      for (int r = 0; r < 4; ++r)
        nrow[wr*64 + mi*16 + lg*4 + r][wc] = rs[r];
    }
  }
  __syncthreads();

  // n per row
  if (tid < 128){
    const ushort* qrow = qg + tid*64;
    const float* kc = kexcl + ((size_t)(bh*NCH + c))*64;
    float dot = 0.f;
    #pragma unroll
    for (int d = 0; d < 64; d += 8){
      s16x8 qv = *(const s16x8*)(qrow + d);
      #pragma unroll
      for (int e = 0; e < 8; ++e) dot += bf2f((ushort)qv[e]) * kc[d + e];
    }
    ninv[tid] = 1.f / (nrow[tid][0] + nrow[tid][1] + dot);
  }

  // stage 2: ctx = Am@V + Q@S^T ; wave owns rows w*32..+31, cols 0..63
  f32x4 a2[2][4] = {};
  #pragma unroll
  for (int kst = 0; kst < 4; ++kst){
    s16x8 pa[2], vv[4];
    #pragma unroll
    for (int mi = 0; mi < 2; ++mi)
      pa[mi] = *(const s16x8*)&Am[w*32 + mi*16 + l15][kst*32 + lg*8];
    #pragma unroll
    for (int ni = 0; ni < 4; ++ni)
      vv[ni] = *(const s16x8*)&VT[ni*16 + l15][kst*32 + lg*8];
    #pragma unroll
    for (int mi = 0; mi < 2; ++mi)
      #pragma unroll
      for (int ni = 0; ni < 4; ++ni)
        a2[mi][ni] = __builtin_amdgcn_mfma_f32_16x16x32_bf16(pa[mi], vv[ni], a2[mi][ni], 0,0,0);
  }
  const float* st = sexcl + ((size_t)(bh*NCH + c))*4096;   // [t][d]
  #pragma unroll
  for (int kst = 0; kst < 2; ++kst){
    s16x8 qa2[2], sb[4];
    #pragma unroll
    for (int mi = 0; mi < 2; ++mi)
      qa2[mi] = *(const s16x8*)(qg + (w*32 + mi*16 + l15)*64 + kst*32 + lg*8);
    #pragma unroll
    for (int ni = 0; ni < 4; ++ni){
      const float* p = st + (ni*16 + l15)*64 + kst*32 + lg*8;
      s16x8 tmp;
      #pragma unroll
      for (int e = 0; e < 8; ++e) tmp[e] = (short)f2bfu(p[e]);
      sb[ni] = tmp;
    }
    #pragma unroll
    for (int mi = 0; mi < 2; ++mi)
      #pragma unroll
      for (int ni = 0; ni < 4; ++ni)
        a2[mi][ni] = __builtin_amdgcn_mfma_f32_16x16x32_bf16(qa2[mi], sb[ni], a2[mi][ni], 0,0,0);
  }
  __syncthreads();

  const int bbi = bh >> 4, h = bh & 15;
  #pragma unroll
  for (int mi = 0; mi < 2; ++mi){
    #pragma unroll
    for (int ni = 0; ni < 4; ++ni){
      int t  = ni*16 + l15;
      int i0 = w*32 + mi*16 + lg*4;
      #pragma unroll
      for (int r = 0; r < 4; ++r){
        int i = i0 + r;
        float v = a2[mi][ni][r] * ninv[i];
        int sg = c*CHUNK + i;
        ctx[((size_t)bbi*S_LEN + sg)*DMODEL + h*HDIM + t] = f2bfu(v);
      }
    }
  }
}

// -------------------------------------------------------------------------
extern "C" void kernel_launch(void* const* d_in, const int* in_sizes, int n_in,
                              void* d_out, int out_size, void* d_ws, size_t ws_size,
                              hipStream_t stream)
{
  const float* x    = (const float*)d_in[0];
  const float* wqk  = (const float*)d_in[1];
  const float* wqkb = (const float*)d_in[2];
  const float* wv   = (const float*)d_in[3];
  const float* wvb  = (const float*)d_in[4];
  const float* wo   = (const float*)d_in[5];
  const float* wob  = (const float*)d_in[6];
  float* out = (float*)d_out;

  char* ws = (char*)d_ws;
  size_t o = 0;
  auto alloc = [&](size_t bytes){ size_t r = o; o += (bytes + 255) & ~(size_t)255; return r; };
  ushort* xbf  = (ushort*)(ws + alloc((size_t)4194304*2));   // reused as ctx later
  ushort* wqkv = (ushort*)(ws + alloc((size_t)3145728*2));
  ushort* wobf = (ushort*)(ws + alloc((size_t)1048576*2));
  float*  bqkv = (float*) (ws + alloc((size_t)3072*4));
  ushort* qbuf = (ushort*)(ws + alloc((size_t)4194304*2));
  ushort* kbuf = (ushort*)(ws + alloc((size_t)4194304*2));
  ushort* vbuf = (ushort*)(ws + alloc((size_t)4194304*2));
  float*  part = (float*) (ws + alloc((size_t)32*16*4096*4));
  float*  kprt = (float*) (ws + alloc((size_t)32*16*64*4));
  ushort* ctxb = xbf;   // x_bf no longer needed after QKV GEMM

  convert_kernel<<<2048, 256, 0, stream>>>(x, wqk, wqkb, wv, wvb, wo, xbf, wqkv, wobf, bqkv);
  gemm_qkv<<<1024, 256, 0, stream>>>(xbf, wqkv, bqkv, 1024, qbuf, kbuf, vbuf);
  chunk_partial<<<512, 256, 0, stream>>>(kbuf, vbuf, part, kprt);
  scan_chunks<<<512, 256, 0, stream>>>(part, kprt);
  chunk_attn<<<512, 256, 0, stream>>>(qbuf, kbuf, vbuf, part, kprt, ctxb);
  gemm_out<<<512, 256, 0, stream>>>(ctxb, wobf, wob, 1024, 1024, out);
}

// Round 7
// 174.809 us; speedup vs baseline: 1.0159x; 1.0031x over previous
//
#include <hip/hip_runtime.h>
#include <hip/hip_bf16.h>

typedef __attribute__((ext_vector_type(4))) float f32x4;
typedef __attribute__((ext_vector_type(8))) short s16x8;
typedef __attribute__((ext_vector_type(4))) short s16x4;

#define DEVI __device__ __forceinline__

constexpr int S_LEN  = 2048;
constexpr int DMODEL = 1024;
constexpr int NH     = 16;
constexpr int HDIM   = 64;
constexpr int CHUNK  = 128;
constexpr int NCH    = S_LEN / CHUNK;   // 16

DEVI ushort f2bfu(float f){
  union { float f; uint u; } v; v.f = f;
  uint u = v.u;
  return (ushort)((u + 0x7fffu + ((u >> 16) & 1u)) >> 16);  // RNE
}
DEVI float bf2f(ushort u){ union { uint u; float f; } v; v.u = ((uint)u) << 16; return v.f; }

// -------------------------------------------------------------------------
// Kernel 1: fp32 -> bf16 conversion of x, weights; build combined qkv bias
// -------------------------------------------------------------------------
struct us4v { ushort a, b, c, d; };

DEVI void cvt_range(const float* __restrict__ src, ushort* __restrict__ dst,
                    long cnt4, long tid, long n){
  const f32x4* s = (const f32x4*)src;
  for (long i = tid; i < cnt4; i += n){
    f32x4 f = s[i];
    us4v o{ f2bfu(f[0]), f2bfu(f[1]), f2bfu(f[2]), f2bfu(f[3]) };
    *(us4v*)(dst + i*4) = o;
  }
}

__global__ __launch_bounds__(256)
void convert_kernel(const float* __restrict__ x,  const float* __restrict__ wqk,
                    const float* __restrict__ wqkb, const float* __restrict__ wv,
                    const float* __restrict__ wvb, const float* __restrict__ wo,
                    ushort* __restrict__ xbf, ushort* __restrict__ wqkv,
                    ushort* __restrict__ wobf, float* __restrict__ bqkv)
{
  long tid = (long)blockIdx.x*blockDim.x + threadIdx.x;
  long n   = (long)gridDim.x*blockDim.x;
  cvt_range(x,   xbf,            4194304/4, tid, n);
  cvt_range(wqk, wqkv,           2097152/4, tid, n);
  cvt_range(wv,  wqkv + 2097152, 1048576/4, tid, n);
  cvt_range(wo,  wobf,           1048576/4, tid, n);
  for (long i = tid; i < 2048; i += n) bqkv[i]        = wqkb[i];
  for (long i = tid; i < 1024; i += n) bqkv[2048 + i] = wvb[i];
}

// -------------------------------------------------------------------------
// Kernel 2: bf16 GEMM  C[M][N] = A[M][K] @ B[N][K]^T + bias
//   BM=256, BN=128, BK=32, 8 waves (512 thr) -> 16 MFMA/wave per K-step at
//   3 gload_lds/thread (vs 4 at 128x128): better compute-per-barrier (m248:
//   2ph 256-class = 655 TF).  Grid 16x24=384, XCD swizzle, bm-major.
//   qkv epilogue: elu+1 on q/k, scatter to [bh][s][d].
// -------------------------------------------------------------------------
__global__ __launch_bounds__(512)
void gemm_qkv(const ushort* __restrict__ A, const ushort* __restrict__ Bm,
              const float* __restrict__ bias, int K,
              ushort* __restrict__ qb, ushort* __restrict__ kb, ushort* __restrict__ vb)
{
  __shared__ __align__(16) ushort ldsA[2][256*32];
  __shared__ __align__(16) ushort ldsB[2][128*32];
  const int tid = threadIdx.x;
  const int w = tid >> 6, l = tid & 63;
  const int l15 = l & 15, lg = l >> 4;
  const int wr = w >> 1, wc = w & 1;          // 4 M-waves x 2 N-waves
  // XCD swizzle: nwg = 384 (divisible by 8); consecutive wg share bm
  const int id = blockIdx.x;
  const int wg = (id & 7) * 48 + (id >> 3);
  const int bm = wg / 24, bn = wg % 24;
  const ushort* Ab = A  + (size_t)bm*256*K;
  const ushort* Bb = Bm + (size_t)bn*128*K;
  const int NT = K >> 5;

  f32x4 acc[4][4] = {};

  auto stage = [&](int buf, int kt){
    const ushort* gA = Ab + kt*32;
    const ushort* gB = Bb + kt*32;
    #pragma unroll
    for (int is = 0; is < 2; ++is){           // A: 256 rows x 2 chunks/thread
      int f = is*512 + tid;
      int row = f >> 2, c8 = (f & 3) * 8;
      __builtin_amdgcn_global_load_lds(
        (const __attribute__((address_space(1))) void*)(gA + (size_t)row*K + c8),
        (__attribute__((address_space(3))) void*)&ldsA[buf][(is*512 + w*64)*8],
        16, 0, 0);
    }
    {                                          // B: 128 rows x 1 chunk/thread
      int f = tid;
      int row = f >> 2, c8 = (f & 3) * 8;
      __builtin_amdgcn_global_load_lds(
        (const __attribute__((address_space(1))) void*)(gB + (size_t)row*K + c8),
        (__attribute__((address_space(3))) void*)&ldsB[buf][(w*64)*8],
        16, 0, 0);
    }
  };

  stage(0, 0);
  __syncthreads();
  int cur = 0;
  for (int kt = 0; kt < NT; ++kt){
    if (kt + 1 < NT) stage(cur ^ 1, kt + 1);
    s16x8 af[4], bfv[4];
    #pragma unroll
    for (int mi = 0; mi < 4; ++mi)
      af[mi] = *(const s16x8*)&ldsA[cur][(wr*64 + mi*16 + l15)*32 + lg*8];
    #pragma unroll
    for (int ni = 0; ni < 4; ++ni)
      bfv[ni] = *(const s16x8*)&ldsB[cur][(wc*64 + ni*16 + l15)*32 + lg*8];
    #pragma unroll
    for (int mi = 0; mi < 4; ++mi)
      #pragma unroll
      for (int ni = 0; ni < 4; ++ni)
        acc[mi][ni] = __builtin_amdgcn_mfma_f32_16x16x32_bf16(af[mi], bfv[ni], acc[mi][ni], 0, 0, 0);
    __syncthreads();
    cur ^= 1;
  }

  #pragma unroll
  for (int mi = 0; mi < 4; ++mi){
    #pragma unroll
    for (int ni = 0; ni < 4; ++ni){
      int col  = bn*128 + wc*64 + ni*16 + l15;
      float bv = bias[col];
      int row0 = bm*256 + wr*64 + mi*16 + lg*4;
      #pragma unroll
      for (int r = 0; r < 4; ++r){
        int tok = row0 + r;
        float val = acc[mi][ni][r] + bv;
        int bb = tok >> 11, ss = tok & 2047;
        if (col < 2048){
          val = val > 0.f ? val + 1.f : __expf(val);   // elu(x)+1
          int h = (col & 1023) >> 6, d = col & 63;
          ushort* dst = (col < 1024) ? qb : kb;
          dst[((size_t)(bb*NH + h)*S_LEN + ss)*HDIM + d] = f2bfu(val);
        } else {
          int cc = col - 2048; int h = cc >> 6, d = cc & 63;
          vb[((size_t)(bb*NH + h)*S_LEN + ss)*HDIM + d] = f2bfu(val);
        }
      }
    }
  }
}

// -------------------------------------------------------------------------
// Kernel 6: bf16 GEMM  out[M][N] = A[M][K] @ B[N][K]^T + bias  (fp32 out)
//   BM=64, BN=128; 1D grid 512 + XCD swizzle
// -------------------------------------------------------------------------
__global__ __launch_bounds__(256)
void gemm_out(const ushort* __restrict__ A, const ushort* __restrict__ Bm,
              const float* __restrict__ bias, int K, int N,
              float* __restrict__ outp)
{
  __shared__ __align__(16) ushort ldsA[2][64*32];
  __shared__ __align__(16) ushort ldsB[2][128*32];
  const int tid = threadIdx.x;
  const int w = tid >> 6, l = tid & 63;
  const int l15 = l & 15, lg = l >> 4;
  const int wr = w >> 1, wc = w & 1;
  const int id = blockIdx.x;                 // nwg = 512
  const int wg = (id & 7) * 64 + (id >> 3);
  const int bm = wg >> 3, bn = wg & 7;
  const ushort* Ab = A  + (size_t)bm*64*K;
  const ushort* Bb = Bm + (size_t)bn*128*K;
  const int NT = K >> 5;

  f32x4 acc[2][4] = {};

  auto stage = [&](int buf, int kt){
    const ushort* gA = Ab + kt*32;
    const ushort* gB = Bb + kt*32;
    {
      int row = tid >> 2, c8 = (tid & 3) * 8;
      __builtin_amdgcn_global_load_lds(
        (const __attribute__((address_space(1))) void*)(gA + (size_t)row*K + c8),
        (__attribute__((address_space(3))) void*)&ldsA[buf][(w*64)*8],
        16, 0, 0);
    }
    #pragma unroll
    for (int is = 0; is < 2; ++is){
      int f = is*256 + tid;
      int row = f >> 2, c8 = (f & 3) * 8;
      __builtin_amdgcn_global_load_lds(
        (const __attribute__((address_space(1))) void*)(gB + (size_t)row*K + c8),
        (__attribute__((address_space(3))) void*)&ldsB[buf][(is*256 + w*64)*8],
        16, 0, 0);
    }
  };

  stage(0, 0);
  __syncthreads();
  int cur = 0;
  for (int kt = 0; kt < NT; ++kt){
    if (kt + 1 < NT) stage(cur ^ 1, kt + 1);
    s16x8 af[2], bfv[4];
    #pragma unroll
    for (int mi = 0; mi < 2; ++mi)
      af[mi] = *(const s16x8*)&ldsA[cur][(wr*32 + mi*16 + l15)*32 + lg*8];
    #pragma unroll
    for (int ni = 0; ni < 4; ++ni)
      bfv[ni] = *(const s16x8*)&ldsB[cur][(wc*64 + ni*16 + l15)*32 + lg*8];
    #pragma unroll
    for (int mi = 0; mi < 2; ++mi)
      #pragma unroll
      for (int ni = 0; ni < 4; ++ni)
        acc[mi][ni] = __builtin_amdgcn_mfma_f32_16x16x32_bf16(af[mi], bfv[ni], acc[mi][ni], 0, 0, 0);
    __syncthreads();
    cur ^= 1;
  }

  #pragma unroll
  for (int mi = 0; mi < 2; ++mi){
    #pragma unroll
    for (int ni = 0; ni < 4; ++ni){
      int col  = bn*128 + wc*64 + ni*16 + l15;
      float bv = bias[col];
      int row0 = bm*64 + wr*32 + mi*16 + lg*4;
      #pragma unroll
      for (int r = 0; r < 4; ++r)
        outp[(size_t)(row0 + r)*N + col] = acc[mi][ni][r] + bv;
    }
  }
}

// -------------------------------------------------------------------------
// Kernel 3: per-chunk partials   part[bh][c][t][d] = sum_s V[s][t]*K[s][d]
//           kpart[bh][c][d]      = sum_s K[s][d]
// -------------------------------------------------------------------------
__global__ __launch_bounds__(256)
void chunk_partial(const ushort* __restrict__ kb, const ushort* __restrict__ vb,
                   float* __restrict__ part, float* __restrict__ kpart)
{
  const int bh = blockIdx.x >> 4, c = blockIdx.x & 15;
  __shared__ __align__(16) float  Ksf[128*64];   // 32 KB fp32
  __shared__ __align__(16) ushort Vs[128*64];    // 16 KB bf16
  __shared__ float kred[4][64];
  const ushort* kg = kb + ((size_t)bh*S_LEN + c*CHUNK)*HDIM;
  const ushort* vg = vb + ((size_t)bh*S_LEN + c*CHUNK)*HDIM;
  const int tid = threadIdx.x;
  #pragma unroll
  for (int ii = 0; ii < 4; ++ii){
    int i = ii*256 + tid;               // 1024 groups of 8 elements
    s16x8 k8 = ((const s16x8*)kg)[i];
    ((s16x8*)Vs)[i] = ((const s16x8*)vg)[i];
    f32x4 lo, hi;
    #pragma unroll
    for (int j = 0; j < 4; ++j){ lo[j] = bf2f((ushort)k8[j]); hi[j] = bf2f((ushort)k8[4+j]); }
    *(f32x4*)&Ksf[i*8]     = lo;
    *(f32x4*)&Ksf[i*8 + 4] = hi;
  }
  __syncthreads();

  const int t0 = (tid >> 4) * 4;
  const int d0 = (tid & 15) * 4;
  f32x4 acc0 = {}, acc1 = {}, acc2 = {}, acc3 = {};
  for (int s = 0; s < 128; ++s){
    f32x4 kv = *(const f32x4*)&Ksf[s*64 + d0];
    s16x4 v4 = *(const s16x4*)&Vs[s*64 + t0];
    acc0 += bf2f((ushort)v4[0]) * kv;
    acc1 += bf2f((ushort)v4[1]) * kv;
    acc2 += bf2f((ushort)v4[2]) * kv;
    acc3 += bf2f((ushort)v4[3]) * kv;
  }
  float* dst = part + ((size_t)(bh*NCH + c))*4096 + (size_t)t0*64 + d0;
  *(f32x4*)&dst[0]   = acc0;
  *(f32x4*)&dst[64]  = acc1;
  *(f32x4*)&dst[128] = acc2;
  *(f32x4*)&dst[192] = acc3;

  // kpart: each quarter-block sums 32 rows of K for all 64 d
  {
    const int d = tid & 63, qq = tid >> 6;
    float s4 = 0.f;
    #pragma unroll 4
    for (int s = qq*32; s < qq*32 + 32; ++s) s4 += Ksf[s*64 + d];
    kred[qq][d] = s4;
  }
  __syncthreads();
  if (tid < 64)
    kpart[((size_t)(bh*NCH + c))*64 + tid] =
        kred[0][tid] + kred[1][tid] + kred[2][tid] + kred[3][tid];
}

// -------------------------------------------------------------------------
// Kernel 4: exclusive scan over chunks (per bh).  512 blocks; all 16 loads
// issued up-front (independent) -> prefix in regs -> stores.
// -------------------------------------------------------------------------
__global__ __launch_bounds__(256)
void scan_chunks(float* __restrict__ part, float* __restrict__ kpart)
{
  const int bh = blockIdx.x >> 4, seg = blockIdx.x & 15;
  const int tid = threadIdx.x;
  const size_t pb = (size_t)bh * NCH * 4096;
  const int e = seg*256 + tid;
  float v[16];
  #pragma unroll
  for (int c = 0; c < 16; ++c) v[c] = part[pb + (size_t)c*4096 + e];
  float r = 0.f;
  #pragma unroll
  for (int c = 0; c < 16; ++c){ part[pb + (size_t)c*4096 + e] = r; r += v[c]; }
  if (seg == 0 && tid < 64){
    const size_t kbase = (size_t)bh * NCH * 64;
    float kv[16];
    #pragma unroll
    for (int c = 0; c < 16; ++c) kv[c] = kpart[kbase + c*64 + tid];
    float kr = 0.f;
    #pragma unroll
    for (int c = 0; c < 16; ++c){ kpart[kbase + c*64 + tid] = kr; kr += kv[c]; }
  }
}

// -------------------------------------------------------------------------
// Kernel 5: per-chunk attention
//   A1 = Q K^T (causal mask, rowsum -> n) ; ctx = A1@V + Q@S_excl ; ctx *= 1/n
// -------------------------------------------------------------------------
__global__ __launch_bounds__(256)
void chunk_attn(const ushort* __restrict__ qb, const ushort* __restrict__ kb,
                const ushort* __restrict__ vb, const float* __restrict__ sexcl,
                const float* __restrict__ kexcl, ushort* __restrict__ ctx)
{
  const int bh = blockIdx.x >> 4, c = blockIdx.x & 15;
  const int tid = threadIdx.x;
  const int w = tid >> 6, l = tid & 63;
  const int l15 = l & 15, lg = l >> 4;

  __shared__ __align__(16) ushort VT[64][136];     // V^T, padded
  __shared__ __align__(16) ushort Am[128][136];    // masked A, bf16, padded
  __shared__ float nrow[128][2];
  __shared__ float ninv[128];

  const ushort* qg = qb + ((size_t)bh*S_LEN + c*CHUNK)*HDIM;
  const ushort* kg = kb + ((size_t)bh*S_LEN + c*CHUNK)*HDIM;
  const ushort* vg = vb + ((size_t)bh*S_LEN + c*CHUNK)*HDIM;

  // transpose V into LDS
  {
    const int s = tid >> 1, t0 = (tid & 1) * 32;
    const ushort* src = vg + s*64 + t0;
    #pragma unroll
    for (int q8 = 0; q8 < 4; ++q8){
      s16x8 vv = *(const s16x8*)(src + q8*8);
      #pragma unroll
      for (int j = 0; j < 8; ++j) VT[t0 + q8*8 + j][s] = (ushort)vv[j];
    }
  }

  // stage 1: A1 = Q K^T, wave (wr,wc) owns 64x64; frags straight from global
  const int wr = w >> 1, wc = w & 1;
  f32x4 a1[4][4] = {};
  #pragma unroll
  for (int kst = 0; kst < 2; ++kst){
    s16x8 qa[4], kv[4];
    #pragma unroll
    for (int mi = 0; mi < 4; ++mi)
      qa[mi] = *(const s16x8*)(qg + (wr*64 + mi*16 + l15)*64 + kst*32 + lg*8);
    #pragma unroll
    for (int ni = 0; ni < 4; ++ni)
      kv[ni] = *(const s16x8*)(kg + (wc*64 + ni*16 + l15)*64 + kst*32 + lg*8);
    #pragma unroll
    for (int mi = 0; mi < 4; ++mi)
      #pragma unroll
      for (int ni = 0; ni < 4; ++ni)
        a1[mi][ni] = __builtin_amdgcn_mfma_f32_16x16x32_bf16(qa[mi], kv[ni], a1[mi][ni], 0,0,0);
  }

  // causal mask + rowsum + store bf16 A to LDS
  #pragma unroll
  for (int mi = 0; mi < 4; ++mi){
    float rs[4] = {0.f, 0.f, 0.f, 0.f};
    #pragma unroll
    for (int ni = 0; ni < 4; ++ni){
      int j = wc*64 + ni*16 + l15;
      #pragma unroll
      for (int r = 0; r < 4; ++r){
        int i = wr*64 + mi*16 + lg*4 + r;
        float v = (j <= i) ? a1[mi][ni][r] : 0.f;
        Am[i][j] = f2bfu(v);
        rs[r] += v;
      }
    }
    #pragma unroll
    for (int r = 0; r < 4; ++r){
      rs[r] += __shfl_xor(rs[r], 1);
      rs[r] += __shfl_xor(rs[r], 2);
      rs[r] += __shfl_xor(rs[r], 4);
      rs[r] += __shfl_xor(rs[r], 8);
    }
    if (l15 == 0){
      #pragma unroll
      for (int r = 0; r < 4; ++r)
        nrow[wr*64 + mi*16 + lg*4 + r][wc] = rs[r];
    }
  }
  __syncthreads();

  // n per row
  if (tid < 128){
    const ushort* qrow = qg + tid*64;
    const float* kc = kexcl + ((size_t)(bh*NCH + c))*64;
    float dot = 0.f;
    #pragma unroll
    for (int d = 0; d < 64; d += 8){
      s16x8 qv = *(const s16x8*)(qrow + d);
      #pragma unroll
      for (int e = 0; e < 8; ++e) dot += bf2f((ushort)qv[e]) * kc[d + e];
    }
    ninv[tid] = 1.f / (nrow[tid][0] + nrow[tid][1] + dot);
  }

  // stage 2: ctx = Am@V + Q@S^T ; wave owns rows w*32..+31, cols 0..63
  f32x4 a2[2][4] = {};
  #pragma unroll
  for (int kst = 0; kst < 4; ++kst){
    s16x8 pa[2], vv[4];
    #pragma unroll
    for (int mi = 0; mi < 2; ++mi)
      pa[mi] = *(const s16x8*)&Am[w*32 + mi*16 + l15][kst*32 + lg*8];
    #pragma unroll
    for (int ni = 0; ni < 4; ++ni)
      vv[ni] = *(const s16x8*)&VT[ni*16 + l15][kst*32 + lg*8];
    #pragma unroll
    for (int mi = 0; mi < 2; ++mi)
      #pragma unroll
      for (int ni = 0; ni < 4; ++ni)
        a2[mi][ni] = __builtin_amdgcn_mfma_f32_16x16x32_bf16(pa[mi], vv[ni], a2[mi][ni], 0,0,0);
  }
  const float* st = sexcl + ((size_t)(bh*NCH + c))*4096;   // [t][d]
  #pragma unroll
  for (int kst = 0; kst < 2; ++kst){
    s16x8 qa2[2], sb[4];
    #pragma unroll
    for (int mi = 0; mi < 2; ++mi)
      qa2[mi] = *(const s16x8*)(qg + (w*32 + mi*16 + l15)*64 + kst*32 + lg*8);
    #pragma unroll
    for (int ni = 0; ni < 4; ++ni){
      const float* p = st + (ni*16 + l15)*64 + kst*32 + lg*8;
      s16x8 tmp;
      #pragma unroll
      for (int e = 0; e < 8; ++e) tmp[e] = (short)f2bfu(p[e]);
      sb[ni] = tmp;
    }
    #pragma unroll
    for (int mi = 0; mi < 2; ++mi)
      #pragma unroll
      for (int ni = 0; ni < 4; ++ni)
        a2[mi][ni] = __builtin_amdgcn_mfma_f32_16x16x32_bf16(qa2[mi], sb[ni], a2[mi][ni], 0,0,0);
  }
  __syncthreads();

  const int bbi = bh >> 4, h = bh & 15;
  #pragma unroll
  for (int mi = 0; mi < 2; ++mi){
    #pragma unroll
    for (int ni = 0; ni < 4; ++ni){
      int t  = ni*16 + l15;
      int i0 = w*32 + mi*16 + lg*4;
      #pragma unroll
      for (int r = 0; r < 4; ++r){
        int i = i0 + r;
        float v = a2[mi][ni][r] * ninv[i];
        int sg = c*CHUNK + i;
        ctx[((size_t)bbi*S_LEN + sg)*DMODEL + h*HDIM + t] = f2bfu(v);
      }
    }
  }
}

// -------------------------------------------------------------------------
extern "C" void kernel_launch(void* const* d_in, const int* in_sizes, int n_in,
                              void* d_out, int out_size, void* d_ws, size_t ws_size,
                              hipStream_t stream)
{
  const float* x    = (const float*)d_in[0];
  const float* wqk  = (const float*)d_in[1];
  const float* wqkb = (const float*)d_in[2];
  const float* wv   = (const float*)d_in[3];
  const float* wvb  = (const float*)d_in[4];
  const float* wo   = (const float*)d_in[5];
  const float* wob  = (const float*)d_in[6];
  float* out = (float*)d_out;

  char* ws = (char*)d_ws;
  size_t o = 0;
  auto alloc = [&](size_t bytes){ size_t r = o; o += (bytes + 255) & ~(size_t)255; return r; };
  ushort* xbf  = (ushort*)(ws + alloc((size_t)4194304*2));   // reused as ctx later
  ushort* wqkv = (ushort*)(ws + alloc((size_t)3145728*2));
  ushort* wobf = (ushort*)(ws + alloc((size_t)1048576*2));
  float*  bqkv = (float*) (ws + alloc((size_t)3072*4));
  ushort* qbuf = (ushort*)(ws + alloc((size_t)4194304*2));
  ushort* kbuf = (ushort*)(ws + alloc((size_t)4194304*2));
  ushort* vbuf = (ushort*)(ws + alloc((size_t)4194304*2));
  float*  part = (float*) (ws + alloc((size_t)32*16*4096*4));
  float*  kprt = (float*) (ws + alloc((size_t)32*16*64*4));
  ushort* ctxb = xbf;   // x_bf no longer needed after QKV GEMM

  convert_kernel<<<2048, 256, 0, stream>>>(x, wqk, wqkb, wv, wvb, wo, xbf, wqkv, wobf, bqkv);
  gemm_qkv<<<384, 512, 0, stream>>>(xbf, wqkv, bqkv, 1024, qbuf, kbuf, vbuf);
  chunk_partial<<<512, 256, 0, stream>>>(kbuf, vbuf, part, kprt);
  scan_chunks<<<512, 256, 0, stream>>>(part, kprt);
  chunk_attn<<<512, 256, 0, stream>>>(qbuf, kbuf, vbuf, part, kprt, ctxb);
  gemm_out<<<512, 256, 0, stream>>>(ctxb, wobf, wob, 1024, 1024, out);
}

// Round 8
// 173.125 us; speedup vs baseline: 1.0258x; 1.0097x over previous
//
#include <hip/hip_runtime.h>
#include <hip/hip_bf16.h>

typedef __attribute__((ext_vector_type(4))) float f32x4;
typedef __attribute__((ext_vector_type(8))) short s16x8;
typedef __attribute__((ext_vector_type(4))) short s16x4;

#define DEVI __device__ __forceinline__

constexpr int S_LEN  = 2048;
constexpr int DMODEL = 1024;
constexpr int NH     = 16;
constexpr int HDIM   = 64;
constexpr int CHUNK  = 128;
constexpr int NCH    = S_LEN / CHUNK;   // 16

DEVI ushort f2bfu(float f){
  union { float f; uint u; } v; v.f = f;
  uint u = v.u;
  return (ushort)((u + 0x7fffu + ((u >> 16) & 1u)) >> 16);  // RNE
}
DEVI float bf2f(ushort u){ union { uint u; float f; } v; v.u = ((uint)u) << 16; return v.f; }

// -------------------------------------------------------------------------
// Kernel 1: fp32 -> bf16 conversion of x, weights; build combined qkv bias
// -------------------------------------------------------------------------
struct us4v { ushort a, b, c, d; };

DEVI void cvt_range(const float* __restrict__ src, ushort* __restrict__ dst,
                    long cnt4, long tid, long n){
  const f32x4* s = (const f32x4*)src;
  for (long i = tid; i < cnt4; i += n){
    f32x4 f = s[i];
    us4v o{ f2bfu(f[0]), f2bfu(f[1]), f2bfu(f[2]), f2bfu(f[3]) };
    *(us4v*)(dst + i*4) = o;
  }
}

__global__ __launch_bounds__(256)
void convert_kernel(const float* __restrict__ x,  const float* __restrict__ wqk,
                    const float* __restrict__ wqkb, const float* __restrict__ wv,
                    const float* __restrict__ wvb, const float* __restrict__ wo,
                    ushort* __restrict__ xbf, ushort* __restrict__ wqkv,
                    ushort* __restrict__ wobf, float* __restrict__ bqkv)
{
  long tid = (long)blockIdx.x*blockDim.x + threadIdx.x;
  long n   = (long)gridDim.x*blockDim.x;
  cvt_range(x,   xbf,            4194304/4, tid, n);
  cvt_range(wqk, wqkv,           2097152/4, tid, n);
  cvt_range(wv,  wqkv + 2097152, 1048576/4, tid, n);
  cvt_range(wo,  wobf,           1048576/4, tid, n);
  for (long i = tid; i < 2048; i += n) bqkv[i]        = wqkb[i];
  for (long i = tid; i < 1024; i += n) bqkv[2048 + i] = wvb[i];
}

// -------------------------------------------------------------------------
// Kernel 2: bf16 GEMM  C[M][N] = A[M][K] @ B[N][K]^T + bias  (128x128 tile)
//   1D grid + bijective XCD swizzle (bm-major); qkv epilogue (elu+1, scatter)
//   Best-measured config: 42.5 us, ~607 TF = 2-phase structural ceiling.
// -------------------------------------------------------------------------
__global__ __launch_bounds__(256)
void gemm_qkv(const ushort* __restrict__ A, const ushort* __restrict__ Bm,
              const float* __restrict__ bias, int K,
              ushort* __restrict__ qb, ushort* __restrict__ kb, ushort* __restrict__ vb)
{
  __shared__ __align__(16) ushort lds[2][2][128*32];
  const int tid = threadIdx.x;
  const int w = tid >> 6, l = tid & 63;
  const int l15 = l & 15, lg = l >> 4;
  const int wr = w >> 1, wc = w & 1;
  // XCD swizzle: nwg = 768 (divisible by 8); consecutive wg share bm (A-panel)
  const int id = blockIdx.x;
  const int wg = (id & 7) * 96 + (id >> 3);
  const int bm = wg / 24, bn = wg % 24;
  const ushort* Ab = A  + (size_t)bm*128*K;
  const ushort* Bb = Bm + (size_t)bn*128*K;
  const int NT = K >> 5;

  f32x4 acc[4][4] = {};

  auto stage = [&](int buf, int kt){
    const ushort* gA = Ab + kt*32;
    const ushort* gB = Bb + kt*32;
    #pragma unroll
    for (int is = 0; is < 2; ++is){
      int f = is*256 + tid;
      int row = f >> 2, c8 = (f & 3) * 8;
      __builtin_amdgcn_global_load_lds(
        (const __attribute__((address_space(1))) void*)(gA + (size_t)row*K + c8),
        (__attribute__((address_space(3))) void*)&lds[buf][0][(is*256 + w*64)*8],
        16, 0, 0);
      __builtin_amdgcn_global_load_lds(
        (const __attribute__((address_space(1))) void*)(gB + (size_t)row*K + c8),
        (__attribute__((address_space(3))) void*)&lds[buf][1][(is*256 + w*64)*8],
        16, 0, 0);
    }
  };

  stage(0, 0);
  __syncthreads();
  int cur = 0;
  for (int kt = 0; kt < NT; ++kt){
    if (kt + 1 < NT) stage(cur ^ 1, kt + 1);
    s16x8 af[4], bfv[4];
    #pragma unroll
    for (int mi = 0; mi < 4; ++mi)
      af[mi] = *(const s16x8*)&lds[cur][0][(wr*64 + mi*16 + l15)*32 + lg*8];
    #pragma unroll
    for (int ni = 0; ni < 4; ++ni)
      bfv[ni] = *(const s16x8*)&lds[cur][1][(wc*64 + ni*16 + l15)*32 + lg*8];
    #pragma unroll
    for (int mi = 0; mi < 4; ++mi)
      #pragma unroll
      for (int ni = 0; ni < 4; ++ni)
        acc[mi][ni] = __builtin_amdgcn_mfma_f32_16x16x32_bf16(af[mi], bfv[ni], acc[mi][ni], 0, 0, 0);
    __syncthreads();
    cur ^= 1;
  }

  #pragma unroll
  for (int mi = 0; mi < 4; ++mi){
    #pragma unroll
    for (int ni = 0; ni < 4; ++ni){
      int col  = bn*128 + wc*64 + ni*16 + l15;
      float bv = bias[col];
      int row0 = bm*128 + wr*64 + mi*16 + lg*4;
      #pragma unroll
      for (int r = 0; r < 4; ++r){
        int tok = row0 + r;
        float val = acc[mi][ni][r] + bv;
        int bb = tok >> 11, ss = tok & 2047;
        if (col < 2048){
          val = val > 0.f ? val + 1.f : __expf(val);   // elu(x)+1
          int h = (col & 1023) >> 6, d = col & 63;
          ushort* dst = (col < 1024) ? qb : kb;
          dst[((size_t)(bb*NH + h)*S_LEN + ss)*HDIM + d] = f2bfu(val);
        } else {
          int cc = col - 2048; int h = cc >> 6, d = cc & 63;
          vb[((size_t)(bb*NH + h)*S_LEN + ss)*HDIM + d] = f2bfu(val);
        }
      }
    }
  }
}

// -------------------------------------------------------------------------
// Kernel 6: bf16 GEMM  out[M][N] = A[M][K] @ B[N][K]^T + bias  (fp32 out)
//   BM=64, BN=128; 1D grid 512 + XCD swizzle (>=2 blocks/CU overlap)
// -------------------------------------------------------------------------
__global__ __launch_bounds__(256)
void gemm_out(const ushort* __restrict__ A, const ushort* __restrict__ Bm,
              const float* __restrict__ bias, int K, int N,
              float* __restrict__ outp)
{
  __shared__ __align__(16) ushort ldsA[2][64*32];
  __shared__ __align__(16) ushort ldsB[2][128*32];
  const int tid = threadIdx.x;
  const int w = tid >> 6, l = tid & 63;
  const int l15 = l & 15, lg = l >> 4;
  const int wr = w >> 1, wc = w & 1;
  const int id = blockIdx.x;                 // nwg = 512
  const int wg = (id & 7) * 64 + (id >> 3);
  const int bm = wg >> 3, bn = wg & 7;
  const ushort* Ab = A  + (size_t)bm*64*K;
  const ushort* Bb = Bm + (size_t)bn*128*K;
  const int NT = K >> 5;

  f32x4 acc[2][4] = {};

  auto stage = [&](int buf, int kt){
    const ushort* gA = Ab + kt*32;
    const ushort* gB = Bb + kt*32;
    {
      int row = tid >> 2, c8 = (tid & 3) * 8;
      __builtin_amdgcn_global_load_lds(
        (const __attribute__((address_space(1))) void*)(gA + (size_t)row*K + c8),
        (__attribute__((address_space(3))) void*)&ldsA[buf][(w*64)*8],
        16, 0, 0);
    }
    #pragma unroll
    for (int is = 0; is < 2; ++is){
      int f = is*256 + tid;
      int row = f >> 2, c8 = (f & 3) * 8;
      __builtin_amdgcn_global_load_lds(
        (const __attribute__((address_space(1))) void*)(gB + (size_t)row*K + c8),
        (__attribute__((address_space(3))) void*)&ldsB[buf][(is*256 + w*64)*8],
        16, 0, 0);
    }
  };

  stage(0, 0);
  __syncthreads();
  int cur = 0;
  for (int kt = 0; kt < NT; ++kt){
    if (kt + 1 < NT) stage(cur ^ 1, kt + 1);
    s16x8 af[2], bfv[4];
    #pragma unroll
    for (int mi = 0; mi < 2; ++mi)
      af[mi] = *(const s16x8*)&ldsA[cur][(wr*32 + mi*16 + l15)*32 + lg*8];
    #pragma unroll
    for (int ni = 0; ni < 4; ++ni)
      bfv[ni] = *(const s16x8*)&ldsB[cur][(wc*64 + ni*16 + l15)*32 + lg*8];
    #pragma unroll
    for (int mi = 0; mi < 2; ++mi)
      #pragma unroll
      for (int ni = 0; ni < 4; ++ni)
        acc[mi][ni] = __builtin_amdgcn_mfma_f32_16x16x32_bf16(af[mi], bfv[ni], acc[mi][ni], 0, 0, 0);
    __syncthreads();
    cur ^= 1;
  }

  #pragma unroll
  for (int mi = 0; mi < 2; ++mi){
    #pragma unroll
    for (int ni = 0; ni < 4; ++ni){
      int col  = bn*128 + wc*64 + ni*16 + l15;
      float bv = bias[col];
      int row0 = bm*64 + wr*32 + mi*16 + lg*4;
      #pragma unroll
      for (int r = 0; r < 4; ++r)
        outp[(size_t)(row0 + r)*N + col] = acc[mi][ni][r] + bv;
    }
  }
}

// -------------------------------------------------------------------------
// Kernel 3: per-chunk partials   part[bh][c][t][d] = sum_s V[s][t]*K[s][d]
//           kpart[bh][c][d]      = sum_s K[s][d]
// -------------------------------------------------------------------------
__global__ __launch_bounds__(256)
void chunk_partial(const ushort* __restrict__ kb, const ushort* __restrict__ vb,
                   float* __restrict__ part, float* __restrict__ kpart)
{
  const int bh = blockIdx.x >> 4, c = blockIdx.x & 15;
  __shared__ __align__(16) float  Ksf[128*64];   // 32 KB fp32
  __shared__ __align__(16) ushort Vs[128*64];    // 16 KB bf16
  __shared__ float kred[4][64];
  const ushort* kg = kb + ((size_t)bh*S_LEN + c*CHUNK)*HDIM;
  const ushort* vg = vb + ((size_t)bh*S_LEN + c*CHUNK)*HDIM;
  const int tid = threadIdx.x;
  #pragma unroll
  for (int ii = 0; ii < 4; ++ii){
    int i = ii*256 + tid;               // 1024 groups of 8 elements
    s16x8 k8 = ((const s16x8*)kg)[i];
    ((s16x8*)Vs)[i] = ((const s16x8*)vg)[i];
    f32x4 lo, hi;
    #pragma unroll
    for (int j = 0; j < 4; ++j){ lo[j] = bf2f((ushort)k8[j]); hi[j] = bf2f((ushort)k8[4+j]); }
    *(f32x4*)&Ksf[i*8]     = lo;
    *(f32x4*)&Ksf[i*8 + 4] = hi;
  }
  __syncthreads();

  const int t0 = (tid >> 4) * 4;
  const int d0 = (tid & 15) * 4;
  f32x4 acc0 = {}, acc1 = {}, acc2 = {}, acc3 = {};
  for (int s = 0; s < 128; ++s){
    f32x4 kv = *(const f32x4*)&Ksf[s*64 + d0];
    s16x4 v4 = *(const s16x4*)&Vs[s*64 + t0];
    acc0 += bf2f((ushort)v4[0]) * kv;
    acc1 += bf2f((ushort)v4[1]) * kv;
    acc2 += bf2f((ushort)v4[2]) * kv;
    acc3 += bf2f((ushort)v4[3]) * kv;
  }
  float* dst = part + ((size_t)(bh*NCH + c))*4096 + (size_t)t0*64 + d0;
  *(f32x4*)&dst[0]   = acc0;
  *(f32x4*)&dst[64]  = acc1;
  *(f32x4*)&dst[128] = acc2;
  *(f32x4*)&dst[192] = acc3;

  // kpart: each quarter-block sums 32 rows of K for all 64 d
  {
    const int d = tid & 63, qq = tid >> 6;
    float s4 = 0.f;
    #pragma unroll 4
    for (int s = qq*32; s < qq*32 + 32; ++s) s4 += Ksf[s*64 + d];
    kred[qq][d] = s4;
  }
  __syncthreads();
  if (tid < 64)
    kpart[((size_t)(bh*NCH + c))*64 + tid] =
        kred[0][tid] + kred[1][tid] + kred[2][tid] + kred[3][tid];
}

// -------------------------------------------------------------------------
// Kernel 4: exclusive scan over chunks (per bh).  512 blocks; all 16 loads
// issued up-front (independent) -> prefix in regs -> stores.
// -------------------------------------------------------------------------
__global__ __launch_bounds__(256)
void scan_chunks(float* __restrict__ part, float* __restrict__ kpart)
{
  const int bh = blockIdx.x >> 4, seg = blockIdx.x & 15;
  const int tid = threadIdx.x;
  const size_t pb = (size_t)bh * NCH * 4096;
  const int e = seg*256 + tid;
  float v[16];
  #pragma unroll
  for (int c = 0; c < 16; ++c) v[c] = part[pb + (size_t)c*4096 + e];
  float r = 0.f;
  #pragma unroll
  for (int c = 0; c < 16; ++c){ part[pb + (size_t)c*4096 + e] = r; r += v[c]; }
  if (seg == 0 && tid < 64){
    const size_t kbase = (size_t)bh * NCH * 64;
    float kv[16];
    #pragma unroll
    for (int c = 0; c < 16; ++c) kv[c] = kpart[kbase + c*64 + tid];
    float kr = 0.f;
    #pragma unroll
    for (int c = 0; c < 16; ++c){ kpart[kbase + c*64 + tid] = kr; kr += kv[c]; }
  }
}

// -------------------------------------------------------------------------
// Kernel 5: per-chunk attention
//   A1 = Q K^T (causal mask, rowsum -> n) ; ctx = A1@V + Q@S_excl ; ctx *= 1/n
// -------------------------------------------------------------------------
__global__ __launch_bounds__(256)
void chunk_attn(const ushort* __restrict__ qb, const ushort* __restrict__ kb,
                const ushort* __restrict__ vb, const float* __restrict__ sexcl,
                const float* __restrict__ kexcl, ushort* __restrict__ ctx)
{
  const int bh = blockIdx.x >> 4, c = blockIdx.x & 15;
  const int tid = threadIdx.x;
  const int w = tid >> 6, l = tid & 63;
  const int l15 = l & 15, lg = l >> 4;

  __shared__ __align__(16) ushort VT[64][136];     // V^T, padded
  __shared__ __align__(16) ushort Am[128][136];    // masked A, bf16, padded
  __shared__ float nrow[128][2];
  __shared__ float ninv[128];

  const ushort* qg = qb + ((size_t)bh*S_LEN + c*CHUNK)*HDIM;
  const ushort* kg = kb + ((size_t)bh*S_LEN + c*CHUNK)*HDIM;
  const ushort* vg = vb + ((size_t)bh*S_LEN + c*CHUNK)*HDIM;

  // transpose V into LDS
  {
    const int s = tid >> 1, t0 = (tid & 1) * 32;
    const ushort* src = vg + s*64 + t0;
    #pragma unroll
    for (int q8 = 0; q8 < 4; ++q8){
      s16x8 vv = *(const s16x8*)(src + q8*8);
      #pragma unroll
      for (int j = 0; j < 8; ++j) VT[t0 + q8*8 + j][s] = (ushort)vv[j];
    }
  }

  // stage 1: A1 = Q K^T, wave (wr,wc) owns 64x64; frags straight from global
  const int wr = w >> 1, wc = w & 1;
  f32x4 a1[4][4] = {};
  #pragma unroll
  for (int kst = 0; kst < 2; ++kst){
    s16x8 qa[4], kv[4];
    #pragma unroll
    for (int mi = 0; mi < 4; ++mi)
      qa[mi] = *(const s16x8*)(qg + (wr*64 + mi*16 + l15)*64 + kst*32 + lg*8);
    #pragma unroll
    for (int ni = 0; ni < 4; ++ni)
      kv[ni] = *(const s16x8*)(kg + (wc*64 + ni*16 + l15)*64 + kst*32 + lg*8);
    #pragma unroll
    for (int mi = 0; mi < 4; ++mi)
      #pragma unroll
      for (int ni = 0; ni < 4; ++ni)
        a1[mi][ni] = __builtin_amdgcn_mfma_f32_16x16x32_bf16(qa[mi], kv[ni], a1[mi][ni], 0,0,0);
  }

  // causal mask + rowsum + store bf16 A to LDS
  #pragma unroll
  for (int mi = 0; mi < 4; ++mi){
    float rs[4] = {0.f, 0.f, 0.f, 0.f};
    #pragma unroll
    for (int ni = 0; ni < 4; ++ni){
      int j = wc*64 + ni*16 + l15;
      #pragma unroll
      for (int r = 0; r < 4; ++r){
        int i = wr*64 + mi*16 + lg*4 + r;
        float v = (j <= i) ? a1[mi][ni][r] : 0.f;
        Am[i][j] = f2bfu(v);
        rs[r] += v;
      }
    }
    #pragma unroll
    for (int r = 0; r < 4; ++r){
      rs[r] += __shfl_xor(rs[r], 1);
      rs[r] += __shfl_xor(rs[r], 2);
      rs[r] += __shfl_xor(rs[r], 4);
      rs[r] += __shfl_xor(rs[r], 8);
    }
    if (l15 == 0){
      #pragma unroll
      for (int r = 0; r < 4; ++r)
        nrow[wr*64 + mi*16 + lg*4 + r][wc] = rs[r];
    }
  }
  __syncthreads();

  // n per row
  if (tid < 128){
    const ushort* qrow = qg + tid*64;
    const float* kc = kexcl + ((size_t)(bh*NCH + c))*64;
    float dot = 0.f;
    #pragma unroll
    for (int d = 0; d < 64; d += 8){
      s16x8 qv = *(const s16x8*)(qrow + d);
      #pragma unroll
      for (int e = 0; e < 8; ++e) dot += bf2f((ushort)qv[e]) * kc[d + e];
    }
    ninv[tid] = 1.f / (nrow[tid][0] + nrow[tid][1] + dot);
  }

  // stage 2: ctx = Am@V + Q@S^T ; wave owns rows w*32..+31, cols 0..63
  f32x4 a2[2][4] = {};
  #pragma unroll
  for (int kst = 0; kst < 4; ++kst){
    s16x8 pa[2], vv[4];
    #pragma unroll
    for (int mi = 0; mi < 2; ++mi)
      pa[mi] = *(const s16x8*)&Am[w*32 + mi*16 + l15][kst*32 + lg*8];
    #pragma unroll
    for (int ni = 0; ni < 4; ++ni)
      vv[ni] = *(const s16x8*)&VT[ni*16 + l15][kst*32 + lg*8];
    #pragma unroll
    for (int mi = 0; mi < 2; ++mi)
      #pragma unroll
      for (int ni = 0; ni < 4; ++ni)
        a2[mi][ni] = __builtin_amdgcn_mfma_f32_16x16x32_bf16(pa[mi], vv[ni], a2[mi][ni], 0,0,0);
  }
  const float* st = sexcl + ((size_t)(bh*NCH + c))*4096;   // [t][d]
  #pragma unroll
  for (int kst = 0; kst < 2; ++kst){
    s16x8 qa2[2], sb[4];
    #pragma unroll
    for (int mi = 0; mi < 2; ++mi)
      qa2[mi] = *(const s16x8*)(qg + (w*32 + mi*16 + l15)*64 + kst*32 + lg*8);
    #pragma unroll
    for (int ni = 0; ni < 4; ++ni){
      const float* p = st + (ni*16 + l15)*64 + kst*32 + lg*8;
      s16x8 tmp;
      #pragma unroll
      for (int e = 0; e < 8; ++e) tmp[e] = (short)f2bfu(p[e]);
      sb[ni] = tmp;
    }
    #pragma unroll
    for (int mi = 0; mi < 2; ++mi)
      #pragma unroll
      for (int ni = 0; ni < 4; ++ni)
        a2[mi][ni] = __builtin_amdgcn_mfma_f32_16x16x32_bf16(qa2[mi], sb[ni], a2[mi][ni], 0,0,0);
  }
  __syncthreads();

  const int bbi = bh >> 4, h = bh & 15;
  #pragma unroll
  for (int mi = 0; mi < 2; ++mi){
    #pragma unroll
    for (int ni = 0; ni < 4; ++ni){
      int t  = ni*16 + l15;
      int i0 = w*32 + mi*16 + lg*4;
      #pragma unroll
      for (int r = 0; r < 4; ++r){
        int i = i0 + r;
        float v = a2[mi][ni][r] * ninv[i];
        int sg = c*CHUNK + i;
        ctx[((size_t)bbi*S_LEN + sg)*DMODEL + h*HDIM + t] = f2bfu(v);
      }
    }
  }
}

// -------------------------------------------------------------------------
extern "C" void kernel_launch(void* const* d_in, const int* in_sizes, int n_in,
                              void* d_out, int out_size, void* d_ws, size_t ws_size,
                              hipStream_t stream)
{
  const float* x    = (const float*)d_in[0];
  const float* wqk  = (const float*)d_in[1];
  const float* wqkb = (const float*)d_in[2];
  const float* wv   = (const float*)d_in[3];
  const float* wvb  = (const float*)d_in[4];
  const float* wo   = (const float*)d_in[5];
  const float* wob  = (const float*)d_in[6];
  float* out = (float*)d_out;

  char* ws = (char*)d_ws;
  size_t o = 0;
  auto alloc = [&](size_t bytes){ size_t r = o; o += (bytes + 255) & ~(size_t)255; return r; };
  ushort* xbf  = (ushort*)(ws + alloc((size_t)4194304*2));   // reused as ctx later
  ushort* wqkv = (ushort*)(ws + alloc((size_t)3145728*2));
  ushort* wobf = (ushort*)(ws + alloc((size_t)1048576*2));
  float*  bqkv = (float*) (ws + alloc((size_t)3072*4));
  ushort* qbuf = (ushort*)(ws + alloc((size_t)4194304*2));
  ushort* kbuf = (ushort*)(ws + alloc((size_t)4194304*2));
  ushort* vbuf = (ushort*)(ws + alloc((size_t)4194304*2));
  float*  part = (float*) (ws + alloc((size_t)32*16*4096*4));
  float*  kprt = (float*) (ws + alloc((size_t)32*16*64*4));
  ushort* ctxb = xbf;   // x_bf no longer needed after QKV GEMM

  convert_kernel<<<2048, 256, 0, stream>>>(x, wqk, wqkb, wv, wvb, wo, xbf, wqkv, wobf, bqkv);
  gemm_qkv<<<768, 256, 0, stream>>>(xbf, wqkv, bqkv, 1024, qbuf, kbuf, vbuf);
  chunk_partial<<<512, 256, 0, stream>>>(kbuf, vbuf, part, kprt);
  scan_chunks<<<512, 256, 0, stream>>>(part, kprt);
  chunk_attn<<<512, 256, 0, stream>>>(qbuf, kbuf, vbuf, part, kprt, ctxb);
  gemm_out<<<512, 256, 0, stream>>>(ctxb, wobf, wob, 1024, 1024, out);
}